// Round 8
// baseline (205.094 us; speedup 1.0000x reference)
//
#include <hip/hip_runtime.h>
#include <stdint.h>

// YOLO loss R8: R6 structure (persistent 1-wave blocks, NT coalesced f4
// loads -> regs -> LDS transpose for BOTH inputs, zero barriers) with a
// DEPTH-2 register pipeline: two staging sets (A/B) keep 15-30 loads
// (14-28 KB) in flight per wave at all times. FIFO vmcnt gives partial
// waits automatically (consume A while B's loads fly). Final reduction
// folded into the main kernel: one spread-free atomicAdd(d_out) per wave.

#define NCLS 20
#define GRID 2816            // 11 blocks/CU at 14336 B LDS
#define TILES 12544          // 802816 cells / 64 cells per tile

typedef float f4 __attribute__((ext_vector_type(4)));

__device__ static inline f4 ldg4nt(const float* p) {
    return __builtin_nontemporal_load((const f4*)p);
}

__global__ __launch_bounds__(64) void yolo_main(
    const float* __restrict__ pred,
    const float* __restrict__ target,
    float* __restrict__ out)
{
    __shared__ float sp[64 * 30];  // 7680 B
    __shared__ float st[64 * 25];  // 6400 B

    const int lane = threadIdx.x;
    const int blk  = blockIdx.x;
    const int n = (TILES - blk + GRID - 1) / GRID;   // 4 or 5 tiles (>=4)

    const float EPS = 1e-6f;

    // two full staging sets: 8 pred f4 + 7 target f4 each
    f4 pa0, pa1, pa2, pa3, pa4, pa5, pa6, pa7;
    f4 ta0, ta1, ta2, ta3, ta4, ta5, ta6;
    f4 pb0, pb1, pb2, pb3, pb4, pb5, pb6, pb7;
    f4 tb0, tb1, tb2, tb3, tb4, tb5, tb6;

#define LOAD_SET(P0,P1,P2,P3,P4,P5,P6,P7,T0,T1,T2,T3,T4,T5,T6,TILE) do {   \
        const float* gp = pred   + (size_t)(TILE) * 1920;                  \
        const float* gt = target + (size_t)(TILE) * 1600;                  \
        P0 = ldg4nt(gp + lane * 4 + 0 * 256);                              \
        P1 = ldg4nt(gp + lane * 4 + 1 * 256);                              \
        P2 = ldg4nt(gp + lane * 4 + 2 * 256);                              \
        P3 = ldg4nt(gp + lane * 4 + 3 * 256);                              \
        P4 = ldg4nt(gp + lane * 4 + 4 * 256);                              \
        P5 = ldg4nt(gp + lane * 4 + 5 * 256);                              \
        P6 = ldg4nt(gp + lane * 4 + 6 * 256);                              \
        if (lane < 32) P7 = ldg4nt(gp + lane * 4 + 7 * 256);               \
        T0 = ldg4nt(gt + lane * 4 + 0 * 256);                              \
        T1 = ldg4nt(gt + lane * 4 + 1 * 256);                              \
        T2 = ldg4nt(gt + lane * 4 + 2 * 256);                              \
        T3 = ldg4nt(gt + lane * 4 + 3 * 256);                              \
        T4 = ldg4nt(gt + lane * 4 + 4 * 256);                              \
        T5 = ldg4nt(gt + lane * 4 + 5 * 256);                              \
        if (lane < 16) T6 = ldg4nt(gt + lane * 4 + 6 * 256);               \
    } while (0)

#define DUMP_SET(P0,P1,P2,P3,P4,P5,P6,P7,T0,T1,T2,T3,T4,T5,T6) do {       \
        *(f4*)(sp + lane * 4 + 0 * 256) = P0;                              \
        *(f4*)(sp + lane * 4 + 1 * 256) = P1;                              \
        *(f4*)(sp + lane * 4 + 2 * 256) = P2;                              \
        *(f4*)(sp + lane * 4 + 3 * 256) = P3;                              \
        *(f4*)(sp + lane * 4 + 4 * 256) = P4;                              \
        *(f4*)(sp + lane * 4 + 5 * 256) = P5;                              \
        *(f4*)(sp + lane * 4 + 6 * 256) = P6;                              \
        if (lane < 32) *(f4*)(sp + lane * 4 + 7 * 256) = P7;               \
        *(f4*)(st + lane * 4 + 0 * 256) = T0;                              \
        *(f4*)(st + lane * 4 + 1 * 256) = T1;                              \
        *(f4*)(st + lane * 4 + 2 * 256) = T2;                              \
        *(f4*)(st + lane * 4 + 3 * 256) = T3;                              \
        *(f4*)(st + lane * 4 + 4 * 256) = T4;                              \
        *(f4*)(st + lane * 4 + 5 * 256) = T5;                              \
        if (lane < 16) *(f4*)(st + lane * 4 + 6 * 256) = T6;               \
    } while (0)

#define LOAD_A(TILE) LOAD_SET(pa0,pa1,pa2,pa3,pa4,pa5,pa6,pa7,ta0,ta1,ta2,ta3,ta4,ta5,ta6,TILE)
#define LOAD_B(TILE) LOAD_SET(pb0,pb1,pb2,pb3,pb4,pb5,pb6,pb7,tb0,tb1,tb2,tb3,tb4,tb5,tb6,TILE)
#define DUMP_A() DUMP_SET(pa0,pa1,pa2,pa3,pa4,pa5,pa6,pa7,ta0,ta1,ta2,ta3,ta4,ta5,ta6)
#define DUMP_B() DUMP_SET(pb0,pb1,pb2,pb3,pb4,pb5,pb6,pb7,tb0,tb1,tb2,tb3,tb4,tb5,tb6)

    auto cell = [&](const float* lp, const float* lt) -> float {
        const float tobj = lt[20];
        const float tx = lt[21], ty = lt[22], tw = lt[23], th = lt[24];

        const float t_x1 = tx - tw * 0.5f, t_x2 = tx + tw * 0.5f;
        const float t_y1 = ty - th * 0.5f, t_y2 = ty + th * 0.5f;
        const float t_area = fabsf((t_x2 - t_x1) * (t_y2 - t_y1));

        float iou[2];
        #pragma unroll
        for (int b = 0; b < 2; ++b) {
            const float bx = lp[NCLS + 5 * b + 1];
            const float by = lp[NCLS + 5 * b + 2];
            const float bw = lp[NCLS + 5 * b + 3];
            const float bh = lp[NCLS + 5 * b + 4];
            const float x1 = bx - bw * 0.5f, x2 = bx + bw * 0.5f;
            const float y1 = by - bh * 0.5f, y2 = by + bh * 0.5f;
            const float iw = fmaxf(fminf(x2, t_x2) - fmaxf(x1, t_x1), 0.0f);
            const float ih = fmaxf(fminf(y2, t_y2) - fmaxf(y1, t_y1), 0.0f);
            const float inter = iw * ih;
            const float a1 = fabsf((x2 - x1) * (y2 - y1));
            iou[b] = inter / (a1 + t_area - inter + EPS);
        }
        const int best = (iou[1] > iou[0]) ? 1 : 0;

        const float bconf = lp[NCLS + 5 * best + 0];
        const float bxv   = lp[NCLS + 5 * best + 1];
        const float byv   = lp[NCLS + 5 * best + 2];
        const float bwv   = lp[NCLS + 5 * best + 3];
        const float bhv   = lp[NCLS + 5 * best + 4];

        const float sgnw = (bwv > 0.f) ? 1.f : ((bwv < 0.f) ? -1.f : 0.f);
        const float sgnh = (bhv > 0.f) ? 1.f : ((bhv < 0.f) ? -1.f : 0.f);
        const float swv = sgnw * sqrtf(fabsf(bwv) + EPS);
        const float shv = sgnh * sqrtf(fabsf(bhv) + EPS);

        float d0 = tobj * bxv - tobj * tx;
        float d1 = tobj * byv - tobj * ty;
        float d2 = tobj * swv - sqrtf(fmaxf(tobj * tw, 0.0f));
        float d3 = tobj * shv - sqrtf(fmaxf(tobj * th, 0.0f));
        float box_loss = d0 * d0 + d1 * d1 + d2 * d2 + d3 * d3;

        const float noobj = 1.0f - tobj;
        float n0 = noobj * (lp[NCLS + 0] - tobj);
        float n1 = noobj * (lp[NCLS + 5] - tobj);
        float no_object_loss = n0 * n0 + n1 * n1;

        float od = tobj * (bconf - tobj);
        float object_loss = od * od;

        float class_loss = 0.0f;
        #pragma unroll
        for (int k = 0; k < NCLS; ++k) {
            float cd = tobj * (lp[k] - lt[k]);
            class_loss += cd * cd;
        }

        return 5.0f * box_loss + object_loss + 0.5f * no_object_loss + class_loss;
    };

    // ---- prologue: tiles 0 and 1 in flight (n >= 4 always)
    LOAD_A(blk);
    LOAD_B(blk + GRID);

    float acc = 0.0f;
    int i = 0;
    while (true) {
        // consume set A (tile i); B's 15 loads stay outstanding
        DUMP_A();
        if (i + 2 < n) LOAD_A(blk + (i + 2) * GRID);
        acc += cell(sp + lane * 30, st + lane * 25);
        __asm__ volatile("" ::: "memory");
        ++i;
        if (i >= n) break;

        // consume set B (tile i); A's refill stays outstanding
        DUMP_B();
        if (i + 2 < n) LOAD_B(blk + (i + 2) * GRID);
        acc += cell(sp + lane * 30, st + lane * 25);
        __asm__ volatile("" ::: "memory");
        ++i;
        if (i >= n) break;
    }

    // wave reduce -> one atomic per wave straight to the scalar output
    #pragma unroll
    for (int off = 32; off > 0; off >>= 1)
        acc += __shfl_down(acc, off, 64);

    if (lane == 0)
        atomicAdd(out, acc);
}

extern "C" void kernel_launch(void* const* d_in, const int* in_sizes, int n_in,
                              void* d_out, int out_size, void* d_ws, size_t ws_size,
                              hipStream_t stream) {
    const float* pred   = (const float*)d_in[0];
    const float* target = (const float*)d_in[1];
    float* out = (float*)d_out;

    // d_out is poisoned before each launch; zero the scalar accumulator
    hipMemsetAsync(out, 0, sizeof(float), stream);

    hipLaunchKernelGGL(yolo_main, dim3(GRID), dim3(64), 0, stream,
                       pred, target, out);
}